// Round 8
// baseline (1515.190 us; speedup 1.0000x reference)
//
#include <hip/hip_runtime.h>
#include <math.h>

#define BB   64
#define SS   1024
#define DD   256
#define H2   512
#define FF   128
#define TT   64
#define NSEG 128
#define DIN  1152
#define G4   2048
#define MROWS 8192   /* B*NSEG */
#define MX   65536   /* B*S   */

typedef __attribute__((ext_vector_type(8))) short bf16x8;
typedef __attribute__((ext_vector_type(4))) float f32x4;

__device__ __forceinline__ unsigned short f2b(float f){
    union { float f; unsigned u; } v; v.f = f;
    unsigned r = v.u + 0x7fffu + ((v.u >> 16) & 1u);
    return (unsigned short)(r >> 16);
}
__device__ __forceinline__ float b2f(unsigned short h){
    union { unsigned u; float f; } v; v.u = ((unsigned)h) << 16;
    return v.f;
}
__device__ __forceinline__ float fsig(float x){
    return 1.f / (1.f + __expf(-x));
}
__device__ __forceinline__ float ftanh(float x){
    float e = __expf(-2.f * fabsf(x));
    float r = (1.f - e) / (1.f + e);
    return x < 0.f ? -r : r;
}

// ---------------- prep kernels ----------------

__global__ void k_cvt(const float* __restrict__ src, unsigned short* __restrict__ dst, int n){
    int i = blockIdx.x * 256 + threadIdx.x;
    if (i < n) dst[i] = f2b(src[i]);
}

// Wf [768][256] rows: 0..127 c1t0 | 128..255 c2t0 | 256..383 c2t1 | 384..511 c3t0 | 512..639 c3t1 | 640..767 c3t2
__global__ void k_wf(const float* __restrict__ w1, const float* __restrict__ w2,
                     const float* __restrict__ w3, unsigned short* __restrict__ Wf){
    int i = blockIdx.x * 256 + threadIdx.x;       // 768*256
    int col = i >> 8, d = i & 255;
    float v;
    if (col < 128)      v = w1[col * 256 + d];
    else if (col < 384) { int f = (col - 128) & 127; int tap = (col - 128) >> 7; v = w2[f * 512 + tap * 256 + d]; }
    else                { int c = col - 384; int f = c & 127; int tap = c >> 7;  v = w3[f * 768 + tap * 256 + d]; }
    Wf[i] = f2b(v);
}

// X[row][d] = bf16(embed[word_ids[row]][d]), row in [0, MX)
__global__ void k_gather(const int* __restrict__ wid, const float* __restrict__ embed,
                         unsigned short* __restrict__ X){
    int i = blockIdx.x * 256 + threadIdx.x;       // MX*64
    int row = i >> 6, d4 = i & 63;
    int w = wid[row];
    float4 v = *(const float4*)(embed + (size_t)w * DD + d4 * 4);
    ushort4 o; o.x = f2b(v.x); o.y = f2b(v.y); o.z = f2b(v.z); o.w = f2b(v.w);
    *(ushort4*)(X + (size_t)row * DD + d4 * 4) = o;
}

// c_w: dec[row][0..256) = mean of 8 X rows
__global__ void k_cw(const unsigned short* __restrict__ X, unsigned short* __restrict__ dec){
    int i = blockIdx.x * 256 + threadIdx.x;       // MROWS*256
    int row = i >> 8, d = i & 255;
    const unsigned short* p = X + (size_t)row * 8 * DD + d;
    float s = 0.f;
#pragma unroll
    for (int t = 0; t < 8; t++) s += b2f(p[t * DD]);
    dec[(size_t)row * DIN + d] = f2b(s * 0.125f);
}

// c_h: dec[row][256..768) = mean of 8 encoder rows
__global__ void k_ch(const float* __restrict__ enc, unsigned short* __restrict__ dec){
    int i = blockIdx.x * 256 + threadIdx.x;       // MROWS*512
    int row = i >> 9, c = i & 511;
    const float* p = enc + (size_t)row * 8 * H2 + c;
    float s = 0.f;
#pragma unroll
    for (int t = 0; t < 8; t++) s += p[t * H2];
    dec[(size_t)row * DIN + 256 + c] = f2b(s * 0.125f);
}

// h0 into Hbuf[0], batch-major: Hbuf[0][b][c]. Clamp so bit14 (sentinel) can never be set.
__global__ void k_h0(const float* __restrict__ enc, unsigned short* __restrict__ Hbuf){
    int i = blockIdx.x * 256 + threadIdx.x;       // 64*512
    int b = i >> 9, c = i & 511;
    float v = (c < 256) ? enc[(size_t)b * SS * H2 + (size_t)(SS - 1) * H2 + c]
                        : enc[(size_t)b * SS * H2 + c];
    v = fminf(fmaxf(v, -1.875f), 1.875f);
    Hbuf[(size_t)b * 512 + c] = f2b(v);
}

// fill Hbuf steps 1..128 with sentinel (bit14 set => "not yet written").
// legit h = sigma*tanh in (-1,1): bf16 bit14 is clear for all |v| < 2.
__global__ void k_fill(uint4* __restrict__ p){
    int i = blockIdx.x * 256 + threadIdx.x;       // 2048*256 = 524288 uint4 = 8 MB
    uint4 v; v.x = v.y = v.z = v.w = 0x7FC07FC0u;
    p[i] = v;
}

// ---------------- fused conv GEMM + max-pool ----------------
// conv-over-taps == GEMM with K extended to taps*256 and A-row shifted by tap.
// Tap-sum accumulates inside the MFMA accumulator; pooling + bias + ReLU in the epilogue.
__global__ __launch_bounds__(256) void gemm_conv_pool(
    const unsigned short* __restrict__ X, const unsigned short* __restrict__ Wf,
    const float* __restrict__ b1, const float* __restrict__ b2, const float* __restrict__ b3,
    unsigned short* __restrict__ dec)
{
    __shared__ unsigned short As[128][40];
    __shared__ unsigned short Bs[128][40];
    const int tid = threadIdx.x;
    const int m0 = blockIdx.x * 128;
    const int w = tid >> 6, lane = tid & 63;
    const int lm = lane & 15, quad = lane >> 4;
    const int wm = (w >> 1) * 64, wn = (w & 1) * 64;
    const int r0 = tid >> 2;            // 0..63
    const int kp = (tid & 3) * 8;       // 0,8,16,24

    const int woffs[3]  = {0, 128, 384};
    const int colofs[3] = {0, 128, 256};
    const float* biases[3] = {b1, b2, b3};

    for (int c = 0; c < 3; c++){
        const int taps = c + 1;
        const f32x4 z = {0.f, 0.f, 0.f, 0.f};
        f32x4 acc[4][4];
#pragma unroll
        for (int i = 0; i < 4; i++)
#pragma unroll
            for (int j = 0; j < 4; j++) acc[i][j] = z;

        for (int kc2 = 0; kc2 < taps * 256; kc2 += 32){
            int tap = kc2 >> 8, kc = kc2 & 255;
            int ra = m0 + r0 + tap;        if (ra > MX - 1) ra = MX - 1;   // clamp (result unused)
            int rb = m0 + 64 + r0 + tap;   if (rb > MX - 1) rb = MX - 1;
            int bw = woffs[c] + tap * 128;
            uint4 a0 = *(const uint4*)(X  + (size_t)ra * DD + kc + kp);
            uint4 a1 = *(const uint4*)(X  + (size_t)rb * DD + kc + kp);
            uint4 b0 = *(const uint4*)(Wf + (size_t)(bw + r0) * DD + kc + kp);
            uint4 b1v= *(const uint4*)(Wf + (size_t)(bw + 64 + r0) * DD + kc + kp);
            __syncthreads();
            *(uint4*)&As[r0][kp] = a0;
            *(uint4*)&As[64 + r0][kp] = a1;
            *(uint4*)&Bs[r0][kp] = b0;
            *(uint4*)&Bs[64 + r0][kp] = b1v;
            __syncthreads();
            bf16x8 af[4], bf[4];
#pragma unroll
            for (int mt = 0; mt < 4; mt++) af[mt] = *(const bf16x8*)&As[wm + mt * 16 + lm][quad * 8];
#pragma unroll
            for (int nt = 0; nt < 4; nt++) bf[nt] = *(const bf16x8*)&Bs[wn + nt * 16 + lm][quad * 8];
#pragma unroll
            for (int mt = 0; mt < 4; mt++)
#pragma unroll
                for (int nt = 0; nt < 4; nt++)
                    acc[mt][nt] = __builtin_amdgcn_mfma_f32_16x16x32_bf16(af[mt], bf[nt], acc[mt][nt], 0, 0, 0);
        }

        const int pmax = 8 - taps;
        const float* bias = biases[c];
#pragma unroll
        for (int nt = 0; nt < 4; nt++){
            int f = wn + nt * 16 + lm;
            float bv = bias[f];
#pragma unroll
            for (int mt = 0; mt < 4; mt++){
                float mx = -1e30f;
#pragma unroll
                for (int r = 0; r < 4; r++){
                    int p = (quad & 1) * 4 + r;
                    if (p <= pmax) mx = fmaxf(mx, acc[mt][nt][r]);
                }
                float po = __shfl_xor(mx, 16);
                mx = fmaxf(mx, po);
                if (!(quad & 1)){
                    int seg = (m0 >> 3) + (wm >> 3) + mt * 2 + (quad >> 1);
                    float o = fmaxf(mx + bv, 0.f);
                    dec[(size_t)seg * DIN + 768 + colofs[c] + f] = f2b(o);
                }
            }
        }
    }
}

// ---------------- generic BT GEMM: C[M][N] = A[M][K] * Bm[N][K]^T, bf16 in/out ----------------
// Also used for the gates GEMM (plain row-major C; coalesced epilogue stores).
__global__ __launch_bounds__(256) void gemm_bt(
    const unsigned short* __restrict__ A, const unsigned short* __restrict__ Bm,
    unsigned short* __restrict__ C, int M, int N, int K)
{
    __shared__ unsigned short As[128][40];
    __shared__ unsigned short Bs[128][40];
    const int tid = threadIdx.x;
    const int m0 = blockIdx.y * 128, n0 = blockIdx.x * 128;
    const int w = tid >> 6, lane = tid & 63;
    const int lm = lane & 15, quad = lane >> 4;
    const int wm = (w >> 1) * 64, wn = (w & 1) * 64;

    const f32x4 z = {0.f, 0.f, 0.f, 0.f};
    f32x4 acc[4][4];
#pragma unroll
    for (int i = 0; i < 4; i++)
#pragma unroll
        for (int j = 0; j < 4; j++) acc[i][j] = z;

    const int r0 = tid >> 2;            // 0..63
    const int kp = (tid & 3) * 8;       // 0,8,16,24 (bf16 units)

    for (int kc = 0; kc < K; kc += 32){
        uint4 a0 = *(const uint4*)(A + (size_t)(m0 + r0) * K + kc + kp);
        uint4 a1 = *(const uint4*)(A + (size_t)(m0 + 64 + r0) * K + kc + kp);
        uint4 b0 = *(const uint4*)(Bm + (size_t)(n0 + r0) * K + kc + kp);
        uint4 b1 = *(const uint4*)(Bm + (size_t)(n0 + 64 + r0) * K + kc + kp);
        __syncthreads();
        *(uint4*)&As[r0][kp] = a0;
        *(uint4*)&As[64 + r0][kp] = a1;
        *(uint4*)&Bs[r0][kp] = b0;
        *(uint4*)&Bs[64 + r0][kp] = b1;
        __syncthreads();
        bf16x8 af[4], bf[4];
#pragma unroll
        for (int mt = 0; mt < 4; mt++) af[mt] = *(const bf16x8*)&As[wm + mt * 16 + lm][quad * 8];
#pragma unroll
        for (int nt = 0; nt < 4; nt++) bf[nt] = *(const bf16x8*)&Bs[wn + nt * 16 + lm][quad * 8];
#pragma unroll
        for (int mt = 0; mt < 4; mt++)
#pragma unroll
            for (int nt = 0; nt < 4; nt++)
                acc[mt][nt] = __builtin_amdgcn_mfma_f32_16x16x32_bf16(af[mt], bf[nt], acc[mt][nt], 0, 0, 0);
    }
#pragma unroll
    for (int mt = 0; mt < 4; mt++){
        int mrow = m0 + wm + mt * 16 + quad * 4;
#pragma unroll
        for (int nt = 0; nt < 4; nt++){
            int ncol = n0 + wn + nt * 16 + lm;
#pragma unroll
            for (int r = 0; r < 4; r++)
                C[(size_t)(mrow + r) * N + ncol] = f2b(acc[mt][nt][r]);
        }
    }
}

// ---------------- persistent LSTM recurrence + fused output projection ----------------
// 4 groups x 16 blocks, 8 waves/block (2/SIMD). Sentinel-on-data sync (bit14), fan-in 16.
// NEW vs r7: (a) gates in PLAIN row-major [m][2048] (gemm epilogue coalesced); the 4 tiny
// pre-activation loads hide under the poll. (b) k_out FUSED into the poll slack: every block
// already stages its group's full h(t) [16x512] in LDS; wave 0 of block (grp,gb) computes
// out row (batch grp*16+gb, t-1) = log_softmax(h(t) . W_fc^T) after publish -- the ~1.5k-cy
// projection is absorbed by the ~5k-cy handoff wait. Loop runs to t=128 (poll+stage+project
// only) to cover h(128). Removes the k_out kernel and its 256MB Wt re-stream entirely.
// W residency: abandoned (r5/r7 proved W loads hide under the poll; not on critical path).
// Hbuf layout per step: [b:64][c:512] bf16, batch-major.
__global__ __attribute__((amdgpu_flat_work_group_size(512, 512), amdgpu_waves_per_eu(2, 2)))
void k_lstm(
    const unsigned short* __restrict__ gxt,  // gate pre-activations, plain [8192][2048] bf16
    const unsigned short* __restrict__ Whh,  // [2048][512] bf16
    unsigned short* __restrict__ Hbuf,       // [129][64*512]
    const float* __restrict__ wfc,           // [64][512] fp32 (used directly, row-major)
    float* __restrict__ out)                 // [8192][64] fp32
{
    __shared__ unsigned short h_lds[2][16 * 512];   // 2 x 16KB, double-buffered

    const int tid = threadIdx.x;
    const int nb = blockIdx.x;
    const int grp = nb >> 4, gb = nb & 15;
    const int w = tid >> 6, lane = tid & 63, lm = lane & 15, quad = lane >> 4;
    const int g = lm & 3;

    // --- W fragments: wave w owns local gate-cols n = w*16 + lm.
    // global W row = (n&3)*512 + gb*32 + (n>>2); fragment ks: cols ks*32 + quad*8 .. +8
    bf16x8 wf[16];
    {
        int n = w * 16 + lm;
        const unsigned short* p = Whh + (size_t)((n & 3) * 512 + gb * 32 + (n >> 2)) * H2 + quad * 8;
#pragma unroll
        for (int ks = 0; ks < 16; ks++) wf[ks] = *(const bf16x8*)(p + ks * 32);
    }

    // gate-col global index for the plain gxt layout
    const int ncol_g = ((w * 16 + lm) & 3) * 512 + gb * 32 + ((w * 16 + lm) >> 2);

    float cst[4] = {0.f, 0.f, 0.f, 0.f};

    union Chunk { unsigned long long q[2]; uint4 u4; };

    for (int t = 0; t <= NSEG; t++){
#pragma unroll
        for (int ks = 0; ks < 16; ks++) asm volatile("" : "+v"(wf[ks]));

        // --- issue this thread's 2 h-chunks (16B each) of the group's 16KB region ---
        const unsigned short* hsrc = Hbuf + (size_t)t * (BB * H2) + (size_t)grp * (16 * H2);
        Chunk ch[2];
#pragma unroll
        for (int j = 0; j < 2; j++){
            const unsigned long long* p = (const unsigned long long*)(hsrc + (size_t)(j * 512 + tid) * 8);
            ch[j].q[0] = __hip_atomic_load(p,     __ATOMIC_RELAXED, __HIP_MEMORY_SCOPE_AGENT);
            ch[j].q[1] = __hip_atomic_load(p + 1, __ATOMIC_RELAXED, __HIP_MEMORY_SCOPE_AGENT);
        }

        // --- gate pre-activations (plain layout; 4 scalar loads, hidden under poll) ---
        unsigned short prv[4];
        if (t < NSEG){
#pragma unroll
            for (int r = 0; r < 4; r++){
                int m = (grp * 16 + quad * 4 + r) * NSEG + t;
                prv[r] = gxt[(size_t)m * G4 + ncol_g];
            }
        }

        // --- sentinel poll with backoff: retry only missing chunks ---
        unsigned pend = 0x3u;
        while (pend){
            unsigned np = 0;
#pragma unroll
            for (int j = 0; j < 2; j++){
                if (pend & (1u << j)){
                    if (((ch[j].q[0] | ch[j].q[1]) & 0x4000400040004000ULL) != 0ULL){
                        const unsigned long long* p = (const unsigned long long*)(hsrc + (size_t)(j * 512 + tid) * 8);
                        ch[j].q[0] = __hip_atomic_load(p,     __ATOMIC_RELAXED, __HIP_MEMORY_SCOPE_AGENT);
                        ch[j].q[1] = __hip_atomic_load(p + 1, __ATOMIC_RELAXED, __HIP_MEMORY_SCOPE_AGENT);
                        np |= 1u << j;
                    }
                }
            }
            pend = np;
            if (pend) __builtin_amdgcn_s_sleep(1);
        }

        // --- stage h to LDS, XOR-swizzled (row = byte>>10; byte ^= (row&7)<<4) ---
        char* hb = (char*)&h_lds[t & 1][0];
#pragma unroll
        for (int j = 0; j < 2; j++){
            unsigned addr = (unsigned)(j * 512 + tid) * 16u;
            addr ^= ((addr >> 10) & 7u) << 4;
            *(uint4*)(hb + addr) = ch[j].u4;
        }
        __syncthreads();

        if (t < NSEG){
            // --- MFMA: A (h) from LDS, B (W) from registers; two 8-deep chains ---
            const unsigned hrowb = (unsigned)lm << 10;
            const unsigned swz = (unsigned)(lm & 7) << 4;
            f32x4 acc0 = {0.f, 0.f, 0.f, 0.f}, acc1 = {0.f, 0.f, 0.f, 0.f};
#pragma unroll
            for (int ks = 0; ks < 16; ks += 2){
                unsigned colb0 = ((unsigned)ks << 6) + ((unsigned)quad << 4);
                unsigned colb1 = colb0 + 64u;
                bf16x8 av0 = *(const bf16x8*)(hb + ((hrowb + colb0) ^ swz));
                bf16x8 av1 = *(const bf16x8*)(hb + ((hrowb + colb1) ^ swz));
                acc0 = __builtin_amdgcn_mfma_f32_16x16x32_bf16(av0, wf[ks],     acc0, 0, 0, 0);
                acc1 = __builtin_amdgcn_mfma_f32_16x16x32_bf16(av1, wf[ks + 1], acc1, 0, 0, 0);
            }

            // --- epilogue: gather i/f/g/o across the 4-lane gate group (g = lm&3) ---
            unsigned short hv4[4];
#pragma unroll
            for (int r = 0; r < 4; r++){
                float a = acc0[r] + acc1[r] + b2f(prv[r]);
                float bsw = __shfl_xor(a, 1);
                float p  = (g & 1) ? bsw : a;     // i or g
                float qq = (g & 1) ? a : bsw;     // f or o
                float c2 = __shfl_xor(p, 2);
                float d2 = __shfl_xor(qq, 2);
                float iv = (g & 2) ? c2 : p;
                float gv = (g & 2) ? p  : c2;
                float fv = (g & 2) ? d2 : qq;
                float ov = (g & 2) ? qq : d2;
                float si = fsig(iv), sf = fsig(fv), so = fsig(ov);
                float cn = sf * cst[r] + si * ftanh(gv);
                cst[r] = cn;
                unsigned short hv = f2b(so * ftanh(cn));
                if (hv & 0x4000u) hv = 0;         // insurance: never emit a sentinel pattern
                hv4[r] = hv;
            }

            // --- publish: shfl-pack 4 cols -> 8B stores (lane lm==0 per quad stores) ---
#pragma unroll
            for (int r = 0; r < 4; r++){
                unsigned v01 = (unsigned)hv4[r] | ((unsigned)(unsigned short)__shfl_xor((int)hv4[r], 4) << 16);
                unsigned v23 = (unsigned)__shfl_xor((int)v01, 8);
                unsigned long long outq = (unsigned long long)v01 | ((unsigned long long)v23 << 32);
                if (lm == 0){
                    int bt = grp * 16 + quad * 4 + r;
                    unsigned long long* dp = (unsigned long long*)
                        (Hbuf + (size_t)(t + 1) * (BB * H2) + (size_t)bt * H2 + gb * 32 + w * 4);
                    __hip_atomic_store(dp, outq, __ATOMIC_RELAXED, __HIP_MEMORY_SCOPE_AGENT);
                }
            }
        }

        // --- fused output projection for row t-1, in the poll slack (wave 0 only) ---
        // h_lds[t&1] holds h(t); out[(b, t-1)] = log_softmax(h(t) . wfc^T). Buffer safe:
        // staging at iter t+1 writes the OTHER parity; overwrite of this parity (iter t+2)
        // is behind barrier(t+1), which waits for wave 0.
        if (w == 0 && t > 0){
            const char* hbp = (const char*)&h_lds[t & 1][0];
            const unsigned rowb = (unsigned)gb << 10;
            const unsigned rx = (unsigned)(gb & 7) << 4;
            const float* wrow = wfc + (size_t)lane * H2;
            float accp = 0.f;
#pragma unroll 8
            for (int c16 = 0; c16 < 64; c16++){
                bf16x8 hvv = *(const bf16x8*)(hbp + ((rowb + (unsigned)c16 * 16u) ^ rx));
                float4 w0 = *(const float4*)(wrow + c16 * 8);
                float4 w1 = *(const float4*)(wrow + c16 * 8 + 4);
                const unsigned short* hs = (const unsigned short*)&hvv;
                accp = fmaf(b2f(hs[0]), w0.x, accp);
                accp = fmaf(b2f(hs[1]), w0.y, accp);
                accp = fmaf(b2f(hs[2]), w0.z, accp);
                accp = fmaf(b2f(hs[3]), w0.w, accp);
                accp = fmaf(b2f(hs[4]), w1.x, accp);
                accp = fmaf(b2f(hs[5]), w1.y, accp);
                accp = fmaf(b2f(hs[6]), w1.z, accp);
                accp = fmaf(b2f(hs[7]), w1.w, accp);
            }
            float mm = accp;
#pragma unroll
            for (int off = 32; off; off >>= 1) mm = fmaxf(mm, __shfl_xor(mm, off));
            float e = expf(accp - mm), ss = e;
#pragma unroll
            for (int off = 32; off; off >>= 1) ss += __shfl_xor(ss, off);
            int orow = (grp * 16 + gb) * NSEG + (t - 1);
            out[(size_t)orow * TT + lane] = accp - mm - logf(ss);
        }
        asm volatile("" ::: "memory");   // pin the h stores inside this iteration
    }
}

// ---------------- launcher ----------------
extern "C" void kernel_launch(void* const* d_in, const int* in_sizes, int n_in,
                              void* d_out, int out_size, void* d_ws, size_t ws_size,
                              hipStream_t stream)
{
    const int*   wid = (const int*)d_in[0];
    const float* emb = (const float*)d_in[1];
    const float* enc = (const float*)d_in[2];
    const float* wc1 = (const float*)d_in[3];
    const float* bc1 = (const float*)d_in[4];
    const float* wc2 = (const float*)d_in[5];
    const float* bc2 = (const float*)d_in[6];
    const float* wc3 = (const float*)d_in[7];
    const float* bc3 = (const float*)d_in[8];
    const float* wih = (const float*)d_in[9];
    const float* whh = (const float*)d_in[10];
    const float* wfc = (const float*)d_in[11];

    char* ws = (char*)d_ws;
    size_t off = 0;
    auto alloc = [&](size_t bytes) -> void* {
        void* p = ws + off; off += (bytes + 255) & ~(size_t)255; return p;
    };
    unsigned short* X    = (unsigned short*)alloc((size_t)MX * DD * 2);      // 33.5 MB (reused as Hbuf)
    unsigned short* dec  = (unsigned short*)alloc((size_t)MROWS * DIN * 2);  // 18.9 MB
    unsigned short* Gb   = (unsigned short*)alloc((size_t)MROWS * G4 * 2);   // 33.5 MB gates
    unsigned short* Wfb  = (unsigned short*)alloc((size_t)768 * 256 * 2);
    unsigned short* Wihb = (unsigned short*)alloc((size_t)G4 * DIN * 2);
    unsigned short* Whhb = (unsigned short*)alloc((size_t)G4 * H2 * 2);
    unsigned short* Hbuf  = X;    // X dead after gemm_conv_pool
    unsigned short* gates = Gb;

    k_cvt<<<(G4 * DIN + 255) / 256, 256, 0, stream>>>(wih, Wihb, G4 * DIN);
    k_cvt<<<(G4 * H2 + 255) / 256, 256, 0, stream>>>(whh, Whhb, G4 * H2);
    k_wf<<<768, 256, 0, stream>>>(wc1, wc2, wc3, Wfb);
    k_gather<<<MX / 4, 256, 0, stream>>>(wid, emb, X);
    k_cw<<<MROWS, 256, 0, stream>>>(X, dec);
    k_ch<<<MROWS * 2, 256, 0, stream>>>(enc, dec);

    // fused conv GEMM + pool: replaces 3x gemm_bt + 3x k_pool (no G materialization)
    gemm_conv_pool<<<512, 256, 0, stream>>>(X, Wfb, bc1, bc2, bc3, dec);

    // X dead after gemm_conv_pool: init Hbuf[0] (h0) and sentinel-fill steps 1..128
    k_h0<<<BB * H2 / 256, 256, 0, stream>>>(enc, Hbuf);
    k_fill<<<2048, 256, 0, stream>>>((uint4*)(Hbuf + BB * H2));

    // gates GEMM in plain row-major (coalesced epilogue)
    gemm_bt<<<dim3(16, 64), 256, 0, stream>>>(dec, Wihb, gates, MROWS, G4, DIN);

    // recurrence + fused projection/log_softmax (k_out eliminated)
    k_lstm<<<64, 512, 0, stream>>>(gates, Whhb, Hbuf, wfc, (float*)d_out);
}